// Round 3
// baseline (262.602 us; speedup 1.0000x reference)
//
#include <hip/hip_runtime.h>

// ---------------------------------------------------------------------------
// CFNO collapsed pipeline (4 dispatches):
//   (1) build_M:    M[16][256] (bf16) + c[16] from W_r/W_i/b_r/b_i  (FFT/linear/IFFT collapsed)
//   (2) patch_gemm: y = M @ patch + c via MFMA (A=M, B=patches -> D=[d][patch],
//                   direct coalesced store, no LDS) -> img[8][16][128][128]
//   (3) conv_stats: depthwise 3x3 conv ONCE -> convbuf + partial sum/sumsq;
//                   last block (atomic counter) reduces -> scale/shift
//   (4) affine:     out = convbuf * scale[d] + shift[d]  (float4, 1:1 threads)
// interp nearest 128->128 is the identity.
// ---------------------------------------------------------------------------

typedef __bf16 bf16x8 __attribute__((ext_vector_type(8)));
typedef float f32x4 __attribute__((ext_vector_type(4)));

#define TWO_PI 6.283185307179586f

// workspace layout (bytes)
#define MB_OFF    0u         // __bf16 Mb[16*256]   (8 KB)
#define CB_OFF    8192u      // float cb[16]
#define SCALE_OFF 8320u      // float scale[16]
#define SHIFT_OFF 8384u      // float shift[16]
#define CNT_OFF   8448u      // unsigned cnt[1]
#define PSUM_OFF  16384u     // float psum[8192]    (32 KB)
#define PSQ_OFF   49152u     // float psq[8192]     (32 KB)
#define IMG_OFF   98304u     // float img[8*16*128*128]  (8 MB)
#define CONV_OFF  8487040u   // float convbuf[8*16*128*128] (8 MB)

// ---------------- kernel 1: build M (bf16) and bias c --------------------
__global__ __launch_bounds__(256) void build_M(
    const float* __restrict__ Wr, const float* __restrict__ br,
    const float* __restrict__ Wi, const float* __restrict__ bi,
    __bf16* __restrict__ Mb, float* __restrict__ cb, unsigned* __restrict__ cnt) {
  __shared__ float costab[256], sintab[256];
  __shared__ float A2[512];  // interleaved (Ar, Ai)
  const int n = blockIdx.x;   // 0..15 output dim
  const int t = threadIdx.x;  // 0..255

  if (n == 0 && t == 0) cnt[0] = 0;  // reset last-block counter every launch

  float sv, cv;
  sincosf((float)t * (TWO_PI / 256.0f), &sv, &cv);
  costab[t] = cv;
  sintab[t] = sv;
  __syncthreads();

  // phase 1: A[n][k] = (1/16) sum_d (Wr+iWi)[d][k] * e^{+2*pi*i*n*d/16}, k = t
  {
    float ar = 0.f, ai = 0.f;
#pragma unroll
    for (int d = 0; d < 16; ++d) {
      int tt = ((n * d) & 15) * 16;
      float cp = costab[tt], sp = sintab[tt];
      float wr = Wr[d * 256 + t], wi = Wi[d * 256 + t];
      ar += wr * cp - wi * sp;
      ai += wr * sp + wi * cp;
    }
    A2[2 * t]     = ar * (1.0f / 16.0f);
    A2[2 * t + 1] = ai * (1.0f / 16.0f);
  }
  if (t == 0) {
    float s = 0.f;
    for (int d = 0; d < 16; ++d) {
      int tt = ((n * d) & 15) * 16;
      s += (br[d] - bi[d]) * costab[tt] - (br[d] + bi[d]) * sintab[tt];
    }
    cb[n] = s * (1.0f / 16.0f);
  }
  __syncthreads();

  // phase 2: M[n][m] = sum_k Ar[k]*cos(2pi k m/256) + Ai[k]*sin(2pi k m/256)
  const float cm = costab[t], sm = sintab[t];
  float c = 1.f, s = 0.f, acc = 0.f;
  for (int k = 0; k < 256; ++k) {
    float ar = A2[2 * k], ai = A2[2 * k + 1];
    acc += ar * c + ai * s;
    float c2 = c * cm - s * sm;
    s = s * cm + c * sm;
    c = c2;
  }
  Mb[n * 256 + t] = (__bf16)acc;
}

// ---------------- kernel 2: patch GEMM via MFMA --------------------------
// one wave = 16 patches x 16 d; A = M rows (d), B = patch features.
// D layout: col(lane&15) = patch, row(g*4+r) = d  -> direct coalesced store.
__global__ __launch_bounds__(256) void patch_gemm(
    const float* __restrict__ x, const __bf16* __restrict__ Mb,
    const float* __restrict__ cb, float* __restrict__ img) {
  const int t = threadIdx.x;
  const int l = t & 63;
  const int wv = t >> 6;
  const int tile = blockIdx.x * 4 + wv;  // 0..8191
  const int b = tile >> 10;              // 0..7
  const int ph = (tile >> 3) & 127;      // patch row
  const int pwb = (tile & 7) * 16;       // patch col base (16 patches/tile)
  const int q = l & 15;                  // A: row d ; B: col patch
  const int g = l >> 4;                  // k-group 0..3

  // A fragments: A[d][k] = M[d][k]; lane row d = q, k = kb*32 + g*8 + j
  bf16x8 mfrag[8];
#pragma unroll
  for (int kb = 0; kb < 8; ++kb) {
    mfrag[kb] = *(const bf16x8*)(Mb + q * 256 + kb * 32 + g * 8);
  }
  // bias: acc reg r corresponds to d = g*4 + r
  const float4 cv4 = ((const float4*)cb)[g];
  f32x4 acc = {cv4.x, cv4.y, cv4.z, cv4.w};

  // B fragment from global: patch = q; k -> (s1 = k>>4, s2 = k&15)
  const float* xbase = x + (size_t)b * 4194304 + (size_t)(ph * 16) * 2048 +
                       (size_t)(pwb + q) * 16 + (g & 1) * 8;
#pragma unroll
  for (int kb = 0; kb < 8; ++kb) {
    const int s1 = kb * 2 + (g >> 1);
    const float* xp = xbase + s1 * 2048;
    const float4 v0 = *(const float4*)xp;
    const float4 v1 = *(const float4*)(xp + 4);
    bf16x8 p;
    p[0] = (__bf16)v0.x; p[1] = (__bf16)v0.y; p[2] = (__bf16)v0.z; p[3] = (__bf16)v0.w;
    p[4] = (__bf16)v1.x; p[5] = (__bf16)v1.y; p[6] = (__bf16)v1.z; p[7] = (__bf16)v1.w;
    acc = __builtin_amdgcn_mfma_f32_16x16x32_bf16(mfrag[kb], p, acc, 0, 0, 0);
  }

  // store: reg r -> d = g*4 + r; 16-lane groups write 64B contiguous
#pragma unroll
  for (int r = 0; r < 4; ++r) {
    const int d = g * 4 + r;
    img[(((size_t)b * 16 + d) * 128 + ph) * 128 + pwb + q] = acc[r];
  }
}

// ---------------- conv helper ---------------------------------------------
__device__ __forceinline__ float conv3x3(const float* __restrict__ plane,
                                         const float* w, int i, int j,
                                         float bias) {
  float acc = bias;
#pragma unroll
  for (int u = 0; u < 3; ++u) {
    const int ii = i + u - 1;
    if (ii < 0 || ii > 127) continue;
#pragma unroll
    for (int v = 0; v < 3; ++v) {
      const int jj = j + v - 1;
      if (jj < 0 || jj > 127) continue;
      acc += w[u * 3 + v] * plane[ii * 128 + jj];
    }
  }
  return acc;
}

// ---------------- kernel 3: conv once + stats + last-block finalize --------
// grid 8192: bx -> d = bx>>9, b = (bx>>6)&7, tile = bx&63 (8x8 tiles of 16x16)
__global__ __launch_bounds__(256) void conv_stats(
    const float* __restrict__ img, const float* __restrict__ cw,
    const float* __restrict__ cbias, const float* __restrict__ gamma,
    const float* __restrict__ beta, float* __restrict__ convbuf,
    float* __restrict__ psum, float* __restrict__ psq,
    float* __restrict__ scale, float* __restrict__ shift,
    unsigned* __restrict__ cnt) {
  const int bx = blockIdx.x;
  const int d = bx >> 9;
  const int b = (bx >> 6) & 7;
  const int tile = bx & 63;
  const int t = threadIdx.x;
  const int i = (tile >> 3) * 16 + (t >> 4);
  const int j = (tile & 7) * 16 + (t & 15);
  const float* plane = img + ((size_t)b * 16 + d) * 16384;
  float w[9];
#pragma unroll
  for (int q = 0; q < 9; ++q) w[q] = cw[d * 9 + q];
  const float v = conv3x3(plane, w, i, j, cbias[d]);
  convbuf[(((size_t)b * 16 + d) * 128 + i) * 128 + j] = v;

  float s1 = v, s2 = v * v;
#pragma unroll
  for (int off = 32; off > 0; off >>= 1) {
    s1 += __shfl_down(s1, off, 64);
    s2 += __shfl_down(s2, off, 64);
  }
  __shared__ float r1[4], r2[4];
  __shared__ bool amLast;
  if ((t & 63) == 0) { r1[t >> 6] = s1; r2[t >> 6] = s2; }
  __syncthreads();
  if (t == 0) {
    psum[bx] = r1[0] + r1[1] + r1[2] + r1[3];
    psq[bx]  = r2[0] + r2[1] + r2[2] + r2[3];
    __threadfence();
    unsigned prev = atomicAdd(cnt, 1u);
    amLast = (prev == 8191u);
  }
  __syncthreads();
  if (amLast) {
    __threadfence();
    const int dd = t >> 4;   // channel
    const int ln = t & 15;
    float a1 = 0.f, a2 = 0.f;
#pragma unroll 4
    for (int k = 0; k < 32; ++k) {
      a1 += psum[dd * 512 + ln + 16 * k];
      a2 += psq [dd * 512 + ln + 16 * k];
    }
#pragma unroll
    for (int off = 8; off > 0; off >>= 1) {
      a1 += __shfl_xor(a1, off, 64);
      a2 += __shfl_xor(a2, off, 64);
    }
    if (ln == 0) {
      const float invN = 1.0f / 131072.0f;
      const float mean = a1 * invN;
      const float var = a2 * invN - mean * mean;
      const float sc = gamma[dd] * rsqrtf(var + 1e-5f);
      scale[dd] = sc;
      shift[dd] = beta[dd] - mean * sc;
    }
  }
}

// ---------------- kernel 4: affine streaming -------------------------------
// exactly 524288 float4 (= 2M floats); one per thread, no loop.
__global__ __launch_bounds__(256) void affine(
    const float4* __restrict__ convbuf, const float* __restrict__ scale,
    const float* __restrict__ shift, float4* __restrict__ out) {
  const int i = blockIdx.x * 256 + threadIdx.x;  // 0..524287
  const int d = (i >> 12) & 15;                  // 4096 float4 per [b][d] plane
  const float4 v = convbuf[i];
  const float sc = scale[d], sh = shift[d];
  float4 o;
  o.x = v.x * sc + sh; o.y = v.y * sc + sh;
  o.z = v.z * sc + sh; o.w = v.w * sc + sh;
  out[i] = o;
}

// ---------------- launcher -------------------------------------------------
extern "C" void kernel_launch(void* const* d_in, const int* in_sizes, int n_in,
                              void* d_out, int out_size, void* d_ws,
                              size_t ws_size, hipStream_t stream) {
  const float* x     = (const float*)d_in[0];
  const float* Wr    = (const float*)d_in[1];
  const float* br    = (const float*)d_in[2];
  const float* Wi    = (const float*)d_in[3];
  const float* bi    = (const float*)d_in[4];
  const float* cw    = (const float*)d_in[5];
  const float* cbias = (const float*)d_in[6];
  const float* gamma = (const float*)d_in[7];
  const float* beta  = (const float*)d_in[8];
  float* out = (float*)d_out;

  char* w = (char*)d_ws;
  __bf16* Mb    = (__bf16*)(w + MB_OFF);
  float* cb     = (float*)(w + CB_OFF);
  float* scale  = (float*)(w + SCALE_OFF);
  float* shift  = (float*)(w + SHIFT_OFF);
  unsigned* cnt = (unsigned*)(w + CNT_OFF);
  float* psum   = (float*)(w + PSUM_OFF);
  float* psq    = (float*)(w + PSQ_OFF);
  float* img    = (float*)(w + IMG_OFF);
  float* convbuf= (float*)(w + CONV_OFF);

  build_M<<<16, 256, 0, stream>>>(Wr, br, Wi, bi, Mb, cb, cnt);
  patch_gemm<<<2048, 256, 0, stream>>>(x, Mb, cb, img);
  conv_stats<<<8192, 256, 0, stream>>>(img, cw, cbias, gamma, beta, convbuf,
                                       psum, psq, scale, shift, cnt);
  affine<<<2048, 256, 0, stream>>>((const float4*)convbuf, scale, shift,
                                   (float4*)out);
}

// Round 4
// 61.632 us; speedup vs baseline: 4.2608x; 4.2608x over previous
//
#include <hip/hip_runtime.h>

// ---------------------------------------------------------------------------
// CFNO collapsed pipeline (5 dispatches, atomic-free):
//   (1) build_M:        M[16][256] (bf16) + c[16]  (FFT/linear/IFFT collapsed)
//   (2) patch_gemm:     y = M @ patch + c via MFMA (A=M, B=patches -> D=[d][patch],
//                       direct coalesced store, no LDS) -> img[8][16][128][128]
//   (3) conv_stats:     depthwise 3x3 conv (recompute), per-block partial sums
//   (4) finalize_stats: 16 blocks -> scale/shift      (no atomics, no fences)
//   (5) conv_norm:      recompute conv, apply BN affine, write out
// interp nearest 128->128 is the identity.
// Lesson (round 2): last-block atomic counter + __threadfence across 8192
// blocks serialized cross-XCD (~230us). Separate tiny dispatch is ~2us.
// ---------------------------------------------------------------------------

typedef __bf16 bf16x8 __attribute__((ext_vector_type(8)));
typedef float f32x4 __attribute__((ext_vector_type(4)));

#define TWO_PI 6.283185307179586f

// workspace layout (bytes)
#define MB_OFF    0u         // __bf16 Mb[16*256]   (8 KB)
#define CB_OFF    8192u      // float cb[16]
#define SCALE_OFF 8320u      // float scale[16]
#define SHIFT_OFF 8384u      // float shift[16]
#define PSUM_OFF  16384u     // float psum[8192]    (32 KB)
#define PSQ_OFF   49152u     // float psq[8192]     (32 KB)
#define IMG_OFF   98304u     // float img[8*16*128*128]  (8 MB)

// ---------------- kernel 1: build M (bf16) and bias c --------------------
__global__ __launch_bounds__(256) void build_M(
    const float* __restrict__ Wr, const float* __restrict__ br,
    const float* __restrict__ Wi, const float* __restrict__ bi,
    __bf16* __restrict__ Mb, float* __restrict__ cb) {
  __shared__ float costab[256], sintab[256];
  __shared__ float A2[512];  // interleaved (Ar, Ai)
  const int n = blockIdx.x;   // 0..15 output dim
  const int t = threadIdx.x;  // 0..255

  float sv, cv;
  sincosf((float)t * (TWO_PI / 256.0f), &sv, &cv);
  costab[t] = cv;
  sintab[t] = sv;
  __syncthreads();

  // phase 1: A[n][k] = (1/16) sum_d (Wr+iWi)[d][k] * e^{+2*pi*i*n*d/16}, k = t
  {
    float ar = 0.f, ai = 0.f;
#pragma unroll
    for (int d = 0; d < 16; ++d) {
      int tt = ((n * d) & 15) * 16;
      float cp = costab[tt], sp = sintab[tt];
      float wr = Wr[d * 256 + t], wi = Wi[d * 256 + t];
      ar += wr * cp - wi * sp;
      ai += wr * sp + wi * cp;
    }
    A2[2 * t]     = ar * (1.0f / 16.0f);
    A2[2 * t + 1] = ai * (1.0f / 16.0f);
  }
  if (t == 0) {
    float s = 0.f;
    for (int d = 0; d < 16; ++d) {
      int tt = ((n * d) & 15) * 16;
      s += (br[d] - bi[d]) * costab[tt] - (br[d] + bi[d]) * sintab[tt];
    }
    cb[n] = s * (1.0f / 16.0f);
  }
  __syncthreads();

  // phase 2: M[n][m] = sum_k Ar[k]*cos(2pi k m/256) + Ai[k]*sin(2pi k m/256)
  const float cm = costab[t], sm = sintab[t];
  float c = 1.f, s = 0.f, acc = 0.f;
  for (int k = 0; k < 256; ++k) {
    float ar = A2[2 * k], ai = A2[2 * k + 1];
    acc += ar * c + ai * s;
    float c2 = c * cm - s * sm;
    s = s * cm + c * sm;
    c = c2;
  }
  Mb[n * 256 + t] = (__bf16)acc;
}

// ---------------- kernel 2: patch GEMM via MFMA --------------------------
// one wave = 16 patches x 16 d; A = M rows (d), B = patch features.
// D layout: col(lane&15) = patch, row(g*4+r) = d  -> direct coalesced store.
__global__ __launch_bounds__(256) void patch_gemm(
    const float* __restrict__ x, const __bf16* __restrict__ Mb,
    const float* __restrict__ cb, float* __restrict__ img) {
  const int t = threadIdx.x;
  const int l = t & 63;
  const int wv = t >> 6;
  const int tile = blockIdx.x * 4 + wv;  // 0..8191
  const int b = tile >> 10;              // 0..7
  const int ph = (tile >> 3) & 127;      // patch row
  const int pwb = (tile & 7) * 16;       // patch col base (16 patches/tile)
  const int q = l & 15;                  // A: row d ; B: col patch
  const int g = l >> 4;                  // k-group 0..3

  // A fragments: A[d][k] = M[d][k]; lane row d = q, k = kb*32 + g*8 + j
  bf16x8 mfrag[8];
#pragma unroll
  for (int kb = 0; kb < 8; ++kb) {
    mfrag[kb] = *(const bf16x8*)(Mb + q * 256 + kb * 32 + g * 8);
  }
  // bias: acc reg r corresponds to d = g*4 + r
  const float4 cv4 = ((const float4*)cb)[g];
  f32x4 acc = {cv4.x, cv4.y, cv4.z, cv4.w};

  // B fragment from global: patch = q; k -> (s1 = k>>4, s2 = k&15)
  const float* xbase = x + (size_t)b * 4194304 + (size_t)(ph * 16) * 2048 +
                       (size_t)(pwb + q) * 16 + (g & 1) * 8;
#pragma unroll
  for (int kb = 0; kb < 8; ++kb) {
    const int s1 = kb * 2 + (g >> 1);
    const float* xp = xbase + s1 * 2048;
    const float4 v0 = *(const float4*)xp;
    const float4 v1 = *(const float4*)(xp + 4);
    bf16x8 p;
    p[0] = (__bf16)v0.x; p[1] = (__bf16)v0.y; p[2] = (__bf16)v0.z; p[3] = (__bf16)v0.w;
    p[4] = (__bf16)v1.x; p[5] = (__bf16)v1.y; p[6] = (__bf16)v1.z; p[7] = (__bf16)v1.w;
    acc = __builtin_amdgcn_mfma_f32_16x16x32_bf16(mfrag[kb], p, acc, 0, 0, 0);
  }

  // store: reg r -> d = g*4 + r; 16-lane groups write 64B contiguous
#pragma unroll
  for (int r = 0; r < 4; ++r) {
    const int d = g * 4 + r;
    img[(((size_t)b * 16 + d) * 128 + ph) * 128 + pwb + q] = acc[r];
  }
}

// ---------------- conv helper ---------------------------------------------
__device__ __forceinline__ float conv3x3(const float* __restrict__ plane,
                                         const float* w, int i, int j,
                                         float bias) {
  float acc = bias;
#pragma unroll
  for (int u = 0; u < 3; ++u) {
    const int ii = i + u - 1;
    if (ii < 0 || ii > 127) continue;
#pragma unroll
    for (int v = 0; v < 3; ++v) {
      const int jj = j + v - 1;
      if (jj < 0 || jj > 127) continue;
      acc += w[u * 3 + v] * plane[ii * 128 + jj];
    }
  }
  return acc;
}

// ---------------- kernel 3: conv + partial stats (atomic-free) -------------
// grid 8192: bx -> d = bx>>9, b = (bx>>6)&7, tile = bx&63 (8x8 tiles of 16x16)
__global__ __launch_bounds__(256) void conv_stats(
    const float* __restrict__ img, const float* __restrict__ cw,
    const float* __restrict__ cbias, float* __restrict__ psum,
    float* __restrict__ psq) {
  const int bx = blockIdx.x;
  const int d = bx >> 9;
  const int b = (bx >> 6) & 7;
  const int tile = bx & 63;
  const int t = threadIdx.x;
  const int i = (tile >> 3) * 16 + (t >> 4);
  const int j = (tile & 7) * 16 + (t & 15);
  const float* plane = img + ((size_t)b * 16 + d) * 16384;
  float w[9];
#pragma unroll
  for (int q = 0; q < 9; ++q) w[q] = cw[d * 9 + q];
  const float v = conv3x3(plane, w, i, j, cbias[d]);

  float s1 = v, s2 = v * v;
#pragma unroll
  for (int off = 32; off > 0; off >>= 1) {
    s1 += __shfl_down(s1, off, 64);
    s2 += __shfl_down(s2, off, 64);
  }
  __shared__ float r1[4], r2[4];
  if ((t & 63) == 0) { r1[t >> 6] = s1; r2[t >> 6] = s2; }
  __syncthreads();
  if (t == 0) {
    psum[bx] = r1[0] + r1[1] + r1[2] + r1[3];
    psq[bx]  = r2[0] + r2[1] + r2[2] + r2[3];
  }
}

// ---------------- kernel 4: finalize stats ---------------------------------
__global__ __launch_bounds__(256) void finalize_stats(
    const float* __restrict__ psum, const float* __restrict__ psq,
    const float* __restrict__ gamma, const float* __restrict__ beta,
    float* __restrict__ scale, float* __restrict__ shift) {
  const int d = blockIdx.x;
  const int t = threadIdx.x;
  float s1 = psum[d * 512 + t] + psum[d * 512 + 256 + t];
  float s2 = psq[d * 512 + t] + psq[d * 512 + 256 + t];
#pragma unroll
  for (int off = 32; off > 0; off >>= 1) {
    s1 += __shfl_down(s1, off, 64);
    s2 += __shfl_down(s2, off, 64);
  }
  __shared__ float r1[4], r2[4];
  if ((t & 63) == 0) { r1[t >> 6] = s1; r2[t >> 6] = s2; }
  __syncthreads();
  if (t == 0) {
    const float S1 = r1[0] + r1[1] + r1[2] + r1[3];
    const float S2 = r2[0] + r2[1] + r2[2] + r2[3];
    const float invN = 1.0f / 131072.0f;
    const float mean = S1 * invN;
    const float var = S2 * invN - mean * mean;
    const float sc = gamma[d] * rsqrtf(var + 1e-5f);
    scale[d] = sc;
    shift[d] = beta[d] - mean * sc;
  }
}

// ---------------- kernel 5: conv + normalize + write -----------------------
__global__ __launch_bounds__(256) void conv_norm(
    const float* __restrict__ img, const float* __restrict__ cw,
    const float* __restrict__ cbias, const float* __restrict__ scale,
    const float* __restrict__ shift, float* __restrict__ out) {
  const int bx = blockIdx.x;
  const int d = bx >> 9;
  const int b = (bx >> 6) & 7;
  const int tile = bx & 63;
  const int t = threadIdx.x;
  const int i = (tile >> 3) * 16 + (t >> 4);
  const int j = (tile & 7) * 16 + (t & 15);
  const float* plane = img + ((size_t)b * 16 + d) * 16384;
  float w[9];
#pragma unroll
  for (int q = 0; q < 9; ++q) w[q] = cw[d * 9 + q];
  const float v = conv3x3(plane, w, i, j, cbias[d]);
  out[(((size_t)b * 16 + d) * 128 + i) * 128 + j] = v * scale[d] + shift[d];
}

// ---------------- launcher -------------------------------------------------
extern "C" void kernel_launch(void* const* d_in, const int* in_sizes, int n_in,
                              void* d_out, int out_size, void* d_ws,
                              size_t ws_size, hipStream_t stream) {
  const float* x     = (const float*)d_in[0];
  const float* Wr    = (const float*)d_in[1];
  const float* br    = (const float*)d_in[2];
  const float* Wi    = (const float*)d_in[3];
  const float* bi    = (const float*)d_in[4];
  const float* cw    = (const float*)d_in[5];
  const float* cbias = (const float*)d_in[6];
  const float* gamma = (const float*)d_in[7];
  const float* beta  = (const float*)d_in[8];
  float* out = (float*)d_out;

  char* w = (char*)d_ws;
  __bf16* Mb   = (__bf16*)(w + MB_OFF);
  float* cb    = (float*)(w + CB_OFF);
  float* scale = (float*)(w + SCALE_OFF);
  float* shift = (float*)(w + SHIFT_OFF);
  float* psum  = (float*)(w + PSUM_OFF);
  float* psq   = (float*)(w + PSQ_OFF);
  float* img   = (float*)(w + IMG_OFF);

  build_M<<<16, 256, 0, stream>>>(Wr, br, Wi, bi, Mb, cb);
  patch_gemm<<<2048, 256, 0, stream>>>(x, Mb, cb, img);
  conv_stats<<<8192, 256, 0, stream>>>(img, cw, cbias, psum, psq);
  finalize_stats<<<16, 256, 0, stream>>>(psum, psq, gamma, beta, scale, shift);
  conv_norm<<<8192, 256, 0, stream>>>(img, cw, cbias, scale, shift, out);
}

// Round 5
// 51.258 us; speedup vs baseline: 5.1232x; 1.2024x over previous
//
#include <hip/hip_runtime.h>

// ---------------------------------------------------------------------------
// CFNO collapsed pipeline (4 dispatches, atomic-free):
//   (1) build_M:    M[16][256] (bf16) + c[16]. Parallel: 64 blocks, 4-way
//                   k-split, table-indexed trig (no serial rotation chain).
//   (2) patch_gemm: y = M @ patch + c via MFMA -> img[8][16][128][128]
//   (3) conv_stats: depthwise 3x3 conv ONCE -> convbuf + per-block psum/psq
//   (4) affine_norm: per-block psum reduce -> scale/shift; convbuf -> out
// interp nearest 128->128 is the identity.
// Lessons: (r2) device-fence+same-line atomic across 8192 blocks = 230us.
//          (r4) patch_gemm is at its 128MB-read floor; epilogue is free.
// ---------------------------------------------------------------------------

typedef __bf16 bf16x8 __attribute__((ext_vector_type(8)));
typedef float f32x4 __attribute__((ext_vector_type(4)));

#define TWO_PI 6.283185307179586f

// workspace layout (bytes)
#define MB_OFF    0u         // __bf16 Mb[16*256]   (8 KB)
#define CB_OFF    8192u      // float cb[16]
#define PSUM_OFF  16384u     // float psum[8192]    (32 KB)
#define PSQ_OFF   49152u     // float psq[8192]     (32 KB)
#define IMG_OFF   98304u     // float img[8*16*128*128]  (8 MB)
#define CONV_OFF  8487040u   // float convbuf[8*16*128*128] (8 MB)

// ---------------- kernel 1: build M (bf16) and bias c ----------------------
// grid 64: n = bx>>2 (output dim), mq = bx&3 (quarter of m-range).
// phase 2: thread t -> m = mq*64 + (t&63), k-range [(t>>6)*64, +64).
// All k-iterations independent (table-indexed exact trig), LDS-combine 4 ways.
__global__ __launch_bounds__(256) void build_M(
    const float* __restrict__ Wr, const float* __restrict__ br,
    const float* __restrict__ Wi, const float* __restrict__ bi,
    __bf16* __restrict__ Mb, float* __restrict__ cb) {
  __shared__ float costab[256], sintab[256];
  __shared__ float A2[512];       // interleaved (Ar, Ai)
  __shared__ float part[4][64];
  const int bx = blockIdx.x;
  const int n = bx >> 2;
  const int mq = bx & 3;
  const int t = threadIdx.x;

  float sv, cv;
  sincosf((float)t * (TWO_PI / 256.0f), &sv, &cv);
  costab[t] = cv;
  sintab[t] = sv;
  __syncthreads();

  // phase 1: A[n][k] = (1/16) sum_d (Wr+iWi)[d][k] * e^{+2*pi*i*n*d/16}, k = t
  {
    float ar = 0.f, ai = 0.f;
#pragma unroll
    for (int d = 0; d < 16; ++d) {
      int tt = ((n * d) & 15) * 16;
      float cp = costab[tt], sp = sintab[tt];
      float wr = Wr[d * 256 + t], wi = Wi[d * 256 + t];
      ar += wr * cp - wi * sp;
      ai += wr * sp + wi * cp;
    }
    A2[2 * t]     = ar * (1.0f / 16.0f);
    A2[2 * t + 1] = ai * (1.0f / 16.0f);
  }
  if (mq == 0 && t == 0) {
    float s = 0.f;
    for (int d = 0; d < 16; ++d) {
      int tt = ((n * d) & 15) * 16;
      s += (br[d] - bi[d]) * costab[tt] - (br[d] + bi[d]) * sintab[tt];
    }
    cb[n] = s * (1.0f / 16.0f);
  }
  __syncthreads();

  // phase 2: M[n][m] = sum_k Ar[k]*costab[(k*m)&255] + Ai[k]*sintab[(k*m)&255]
  const int m = mq * 64 + (t & 63);
  const int k0 = (t >> 6) * 64;
  float acc = 0.f;
#pragma unroll 4
  for (int kk = 0; kk < 64; ++kk) {
    const int k = k0 + kk;
    const int idx = (k * m) & 255;
    acc += A2[2 * k] * costab[idx] + A2[2 * k + 1] * sintab[idx];
  }
  part[t >> 6][t & 63] = acc;
  __syncthreads();
  if (t < 64) {
    const float r = part[0][t] + part[1][t] + part[2][t] + part[3][t];
    Mb[n * 256 + mq * 64 + t] = (__bf16)r;
  }
}

// ---------------- kernel 2: patch GEMM via MFMA ----------------------------
// one wave = 16 patches x 16 d; A = M rows (d), B = patch features.
// D layout: col(lane&15) = patch, row(g*4+r) = d  -> direct coalesced store.
__global__ __launch_bounds__(256) void patch_gemm(
    const float* __restrict__ x, const __bf16* __restrict__ Mb,
    const float* __restrict__ cb, float* __restrict__ img) {
  const int t = threadIdx.x;
  const int l = t & 63;
  const int wv = t >> 6;
  const int tile = blockIdx.x * 4 + wv;  // 0..8191
  const int b = tile >> 10;              // 0..7
  const int ph = (tile >> 3) & 127;      // patch row
  const int pwb = (tile & 7) * 16;       // patch col base (16 patches/tile)
  const int q = l & 15;                  // A: row d ; B: col patch
  const int g = l >> 4;                  // k-group 0..3

  // A fragments: A[d][k] = M[d][k]; lane row d = q, k = kb*32 + g*8 + j
  bf16x8 mfrag[8];
#pragma unroll
  for (int kb = 0; kb < 8; ++kb) {
    mfrag[kb] = *(const bf16x8*)(Mb + q * 256 + kb * 32 + g * 8);
  }
  // bias: acc reg r corresponds to d = g*4 + r
  const float4 cv4 = ((const float4*)cb)[g];
  f32x4 acc = {cv4.x, cv4.y, cv4.z, cv4.w};

  // B fragment from global: patch = q; k -> (s1 = k>>4, s2 = k&15)
  const float* xbase = x + (size_t)b * 4194304 + (size_t)(ph * 16) * 2048 +
                       (size_t)(pwb + q) * 16 + (g & 1) * 8;
#pragma unroll
  for (int kb = 0; kb < 8; ++kb) {
    const int s1 = kb * 2 + (g >> 1);
    const float* xp = xbase + s1 * 2048;
    const float4 v0 = *(const float4*)xp;
    const float4 v1 = *(const float4*)(xp + 4);
    bf16x8 p;
    p[0] = (__bf16)v0.x; p[1] = (__bf16)v0.y; p[2] = (__bf16)v0.z; p[3] = (__bf16)v0.w;
    p[4] = (__bf16)v1.x; p[5] = (__bf16)v1.y; p[6] = (__bf16)v1.z; p[7] = (__bf16)v1.w;
    acc = __builtin_amdgcn_mfma_f32_16x16x32_bf16(mfrag[kb], p, acc, 0, 0, 0);
  }

  // store: reg r -> d = g*4 + r; 16-lane groups write 64B contiguous
#pragma unroll
  for (int r = 0; r < 4; ++r) {
    const int d = g * 4 + r;
    img[(((size_t)b * 16 + d) * 128 + ph) * 128 + pwb + q] = acc[r];
  }
}

// ---------------- conv helper ----------------------------------------------
__device__ __forceinline__ float conv3x3(const float* __restrict__ plane,
                                         const float* w, int i, int j,
                                         float bias) {
  float acc = bias;
#pragma unroll
  for (int u = 0; u < 3; ++u) {
    const int ii = i + u - 1;
    if (ii < 0 || ii > 127) continue;
#pragma unroll
    for (int v = 0; v < 3; ++v) {
      const int jj = j + v - 1;
      if (jj < 0 || jj > 127) continue;
      acc += w[u * 3 + v] * plane[ii * 128 + jj];
    }
  }
  return acc;
}

// ---------------- kernel 3: conv ONCE -> convbuf + partial stats ------------
// grid 8192: bx -> d = bx>>9, b = (bx>>6)&7, tile = bx&63.
// 8x32 tiles: full 128B row segments for both loads and stores.
__global__ __launch_bounds__(256) void conv_stats(
    const float* __restrict__ img, const float* __restrict__ cw,
    const float* __restrict__ cbias, float* __restrict__ convbuf,
    float* __restrict__ psum, float* __restrict__ psq) {
  const int bx = blockIdx.x;
  const int d = bx >> 9;
  const int b = (bx >> 6) & 7;
  const int tile = bx & 63;
  const int t = threadIdx.x;
  const int i = (tile >> 2) * 8 + (t >> 5);   // 16 row-blocks of 8
  const int j = (tile & 3) * 32 + (t & 31);   // 4 col-blocks of 32 (128B)
  const float* plane = img + ((size_t)b * 16 + d) * 16384;
  float w[9];
#pragma unroll
  for (int q = 0; q < 9; ++q) w[q] = cw[d * 9 + q];
  const float v = conv3x3(plane, w, i, j, cbias[d]);
  convbuf[(((size_t)b * 16 + d) * 128 + i) * 128 + j] = v;

  float s1 = v, s2 = v * v;
#pragma unroll
  for (int off = 32; off > 0; off >>= 1) {
    s1 += __shfl_down(s1, off, 64);
    s2 += __shfl_down(s2, off, 64);
  }
  __shared__ float r1[4], r2[4];
  if ((t & 63) == 0) { r1[t >> 6] = s1; r2[t >> 6] = s2; }
  __syncthreads();
  if (t == 0) {
    psum[bx] = r1[0] + r1[1] + r1[2] + r1[3];
    psq[bx]  = r2[0] + r2[1] + r2[2] + r2[3];
  }
}

// ---------------- kernel 4: per-block finalize + affine stream -------------
// grid 2048: block covers 1024 consecutive float4 (quarter of one (b,d) plane)
// -> single d per block; block redundantly reduces that channel's psums.
__global__ __launch_bounds__(256) void affine_norm(
    const float4* __restrict__ convbuf, const float* __restrict__ psum,
    const float* __restrict__ psq, const float* __restrict__ gamma,
    const float* __restrict__ beta, float4* __restrict__ out) {
  const int t = threadIdx.x;
  const int i = blockIdx.x * 256 + t;   // float4 index, 0..524287
  const int d = (i >> 12) & 15;         // 4096 float4 per (b,d) plane

  const float4 v = convbuf[i];          // issue load early

  float a1 = psum[d * 512 + t] + psum[d * 512 + 256 + t];
  float a2 = psq [d * 512 + t] + psq [d * 512 + 256 + t];
#pragma unroll
  for (int off = 32; off > 0; off >>= 1) {
    a1 += __shfl_down(a1, off, 64);
    a2 += __shfl_down(a2, off, 64);
  }
  __shared__ float r1[4], r2[4];
  __shared__ float sc_sh, sh_sh;
  if ((t & 63) == 0) { r1[t >> 6] = a1; r2[t >> 6] = a2; }
  __syncthreads();
  if (t == 0) {
    const float S1 = r1[0] + r1[1] + r1[2] + r1[3];
    const float S2 = r2[0] + r2[1] + r2[2] + r2[3];
    const float invN = 1.0f / 131072.0f;
    const float mean = S1 * invN;
    const float var = S2 * invN - mean * mean;
    const float sc = gamma[d] * rsqrtf(var + 1e-5f);
    sc_sh = sc;
    sh_sh = beta[d] - mean * sc;
  }
  __syncthreads();
  const float sc = sc_sh, sh = sh_sh;
  float4 o;
  o.x = v.x * sc + sh; o.y = v.y * sc + sh;
  o.z = v.z * sc + sh; o.w = v.w * sc + sh;
  out[i] = o;
}

// ---------------- launcher --------------------------------------------------
extern "C" void kernel_launch(void* const* d_in, const int* in_sizes, int n_in,
                              void* d_out, int out_size, void* d_ws,
                              size_t ws_size, hipStream_t stream) {
  const float* x     = (const float*)d_in[0];
  const float* Wr    = (const float*)d_in[1];
  const float* br    = (const float*)d_in[2];
  const float* Wi    = (const float*)d_in[3];
  const float* bi    = (const float*)d_in[4];
  const float* cw    = (const float*)d_in[5];
  const float* cbias = (const float*)d_in[6];
  const float* gamma = (const float*)d_in[7];
  const float* beta  = (const float*)d_in[8];
  float* out = (float*)d_out;

  char* w = (char*)d_ws;
  __bf16* Mb    = (__bf16*)(w + MB_OFF);
  float* cb     = (float*)(w + CB_OFF);
  float* psum   = (float*)(w + PSUM_OFF);
  float* psq    = (float*)(w + PSQ_OFF);
  float* img    = (float*)(w + IMG_OFF);
  float* convbuf= (float*)(w + CONV_OFF);

  build_M<<<64, 256, 0, stream>>>(Wr, br, Wi, bi, Mb, cb);
  patch_gemm<<<2048, 256, 0, stream>>>(x, Mb, cb, img);
  conv_stats<<<8192, 256, 0, stream>>>(img, cw, cbias, convbuf, psum, psq);
  affine_norm<<<2048, 256, 0, stream>>>((const float4*)convbuf, psum, psq,
                                        gamma, beta, (float4*)out);
}